// Round 1
// 1966.897 us; speedup vs baseline: 1.4822x; 1.4822x over previous
//
#include <hip/hip_runtime.h>
#include <stdint.h>

#define Bsz 64
#define Tsz 512
#define HD  512
#define GROUPS 4
#define MEMBERS 16
#define BROWS 16          // batch rows per group
#define JCH 32            // hidden units per workgroup
#define NWG (GROUPS*MEMBERS)
#define NTHR 512
#define LROW 520          // LDS row stride in halfwords (512 + 8 pad)
#define LROWD 260         // same in dwords
#define HSLOT (Bsz*HD/2)  // 16384 u64 per parity buffer

typedef __attribute__((ext_vector_type(8))) short bf16x8;
typedef __attribute__((ext_vector_type(4))) float f32x4;
typedef __attribute__((ext_vector_type(4))) uint32_t u32x4;
typedef __attribute__((ext_vector_type(2))) uint32_t u32x2;

__device__ __forceinline__ uint32_t f2bf(float f) {
  uint32_t u = __builtin_bit_cast(uint32_t, f);
  return (u + 0x7FFFu + ((u >> 16) & 1u)) >> 16;   // RNE f32 -> bf16
}

// Load 8 consecutive f32 from W[row][k0..k0+7], convert to a bf16x8 MFMA B-fragment.
__device__ __forceinline__ bf16x8 ldwf(const float* __restrict__ W, int row, int k0) {
  const f32x4 a = *reinterpret_cast<const f32x4*>(W + (size_t)row * HD + k0);
  const f32x4 b = *reinterpret_cast<const f32x4*>(W + (size_t)row * HD + k0 + 4);
  bf16x8 r;
  r[0] = (short)f2bf(a.x); r[1] = (short)f2bf(a.y);
  r[2] = (short)f2bf(a.z); r[3] = (short)f2bf(a.w);
  r[4] = (short)f2bf(b.x); r[5] = (short)f2bf(b.y);
  r[6] = (short)f2bf(b.z); r[7] = (short)f2bf(b.w);
  return r;
}

// Prologue-only: stage x[b0..b0+15][t][:] (f32) into LDS as bf16 in one shot.
__device__ __forceinline__ void stage_x(const float* __restrict__ x, int t, int b0,
                                        uint32_t* xl, int tid) {
#pragma unroll
  for (int i = 0; i < 4; ++i) {
    const int fl = tid + i * 512;        // float4 index over 16x128
    const int row = fl >> 7;
    const int c4 = fl & 127;
    const f32x4 v = *reinterpret_cast<const f32x4*>(
        x + ((size_t)(b0 + row) * Tsz + t) * HD + c4 * 4);
    u32x2 w;
    w.x = f2bf(v.x) | (f2bf(v.y) << 16);
    w.y = f2bf(v.z) | (f2bf(v.w) << 16);
    *reinterpret_cast<u32x2*>(xl + row * LROWD + c4 * 2) = w;
  }
}

// Exchange buffer hbx: u64[2][Bsz][256]. Each u64 = (tag << 32) | (2 packed bf16).
// h(s) lives at parity s&1 with tag s+1; h(-1)=h0 at parity 1 with tag 0.
__global__ void gru_init(const float* __restrict__ h0, uint64_t* __restrict__ hbx) {
  const int i = blockIdx.x * 256 + threadIdx.x;
  if (i < HSLOT) {
    const float a = h0[2 * i], b = h0[2 * i + 1];
    hbx[HSLOT + i] = (uint64_t)(f2bf(a) | (f2bf(b) << 16));  // parity 1: tag 0 | h0
    hbx[i] = 0xFFFFFFFF00000000ull;                          // parity 0: never-matching tag
  }
}

__global__ void __launch_bounds__(NTHR) gru_persist(
    const float* __restrict__ x, const float* __restrict__ h0,
    const float* __restrict__ Wih, const float* __restrict__ Whh,
    const float* __restrict__ bih, const float* __restrict__ bhh,
    const int* __restrict__ lens,
    float* __restrict__ out, float* __restrict__ outh,
    uint64_t* __restrict__ hbx) {
  __shared__ alignas(16) unsigned short x_lds[2][BROWS * LROW];
  __shared__ alignas(16) unsigned short h_lds[BROWS * LROW];
  __shared__ alignas(16) float s_lds[BROWS][4][JCH];   // [row][r,z,i_n,h_n][j]

  const int tid = threadIdx.x;
  const int lane = tid & 63;
  const int wv = tid >> 6;                 // wave 0..7
  const int gid = blockIdx.x & 3;          // batch group
  const int mem = blockIdx.x >> 2;         // member within group
  const int b0 = gid * BROWS;
  const int j0 = mem * JCH;

  // ---- per-thread gate-phase constants (thread <-> (row, j) fixed) ----
  const int grow = tid >> 5;               // local batch row 0..15
  const int gj = tid & 31;                 // local hidden 0..31
  const float br = bih[j0 + gj] + bhh[j0 + gj];
  const float bz = bih[512 + j0 + gj] + bhh[512 + j0 + gj];
  const float bi_n = bih[1024 + j0 + gj];
  const float bh_n = bhh[1024 + j0 + gj];
  float hprev = h0[(size_t)(b0 + grow) * HD + j0 + gj];   // f32 running state in-register
  const int lenr = lens[b0 + grow];        // int32 per harness integer convention

  // ---- poll-phase constants: thread polls one 64B line (8 u64 = 16 h cols) ----
  const int prow = tid >> 5;               // local batch row 0..15
  const int pcu = (tid & 31) * 8;          // first u64 (col-pair) index in row
  const uint64_t* psrc = hbx + (size_t)(b0 + prow) * 256 + pcu;

  // ---- stationary weight fragments (held in VGPRs for the whole scan) ----
  const int c = lane & 15;                 // MFMA col (gate) / A-row (batch)
  const int kg = lane >> 4;                // k-group 0..3
  bf16x8 wfa[16], wfb[16];
  if (wv < 4) {                            // combined r/z: wv0,1 = r cols, wv2,3 = z cols
    const int wrow = (wv >> 1) * 512 + j0 + (wv & 1) * 16 + c;
#pragma unroll
    for (int ks = 0; ks < 16; ++ks) {
      const int k0 = ks * 32 + kg * 8;
      wfa[ks] = ldwf(Wih, wrow, k0);
      wfb[ks] = ldwf(Whh, wrow, k0);
    }
  } else if (wv < 6) {                     // i_n
    const int wrow = 1024 + j0 + (wv - 4) * 16 + c;
#pragma unroll
    for (int ks = 0; ks < 16; ++ks) wfa[ks] = ldwf(Wih, wrow, ks * 32 + kg * 8);
  } else {                                 // h_n
    const int wrow = 1024 + j0 + (wv - 6) * 16 + c;
#pragma unroll
    for (int ks = 0; ks < 16; ++ks) wfb[ks] = ldwf(Whh, wrow, ks * 32 + kg * 8);
  }

  stage_x(x, 0, b0, (uint32_t*)&x_lds[0][0], tid);   // prologue

  for (int t = 0; t < Tsz; ++t) {
    // ---- phase A1: issue x(t+1) loads early; latency hides under the poll ----
    f32x4 xr[4];
    if (t + 1 < Tsz) {
#pragma unroll
      for (int i = 0; i < 4; ++i) {
        const int fl = tid + i * 512;
        const int row = fl >> 7;
        const int c4 = fl & 127;
        xr[i] = *reinterpret_cast<const f32x4*>(
            x + ((size_t)(b0 + row) * Tsz + (t + 1)) * HD + c4 * 4);
      }
    }

    // ---- phase A2: poll tagged h(t-1); the data is its own flag (1 L3 trip) ----
    {
      const uint64_t* src = psrc + (size_t)((t + 1) & 1) * HSLOT;
      const uint32_t want = (uint32_t)t;   // tag of h(t-1)
      uint64_t v[8];
      for (;;) {
        bool ok = true;
#pragma unroll
        for (int i = 0; i < 8; ++i)
          v[i] = __hip_atomic_load(src + i, __ATOMIC_RELAXED, __HIP_MEMORY_SCOPE_AGENT);
#pragma unroll
        for (int i = 0; i < 8; ++i) ok &= ((uint32_t)(v[i] >> 32) == want);
        if (ok) break;
      }
      uint32_t* dst = (uint32_t*)&h_lds[0] + prow * LROWD + pcu;
      u32x4 w0 = {(uint32_t)v[0], (uint32_t)v[1], (uint32_t)v[2], (uint32_t)v[3]};
      u32x4 w1 = {(uint32_t)v[4], (uint32_t)v[5], (uint32_t)v[6], (uint32_t)v[7]};
      *reinterpret_cast<u32x4*>(dst) = w0;
      *reinterpret_cast<u32x4*>(dst + 4) = w1;
    }

    // ---- phase A3: convert + write staged x(t+1) (loads have landed by now) ----
    if (t + 1 < Tsz) {
      uint32_t* xl = (uint32_t*)&x_lds[(t + 1) & 1][0];
#pragma unroll
      for (int i = 0; i < 4; ++i) {
        const int fl = tid + i * 512;
        const int row = fl >> 7;
        const int c4 = fl & 127;
        u32x2 w;
        w.x = f2bf(xr[i].x) | (f2bf(xr[i].y) << 16);
        w.y = f2bf(xr[i].z) | (f2bf(xr[i].w) << 16);
        *reinterpret_cast<u32x2*>(xl + row * LROWD + c4 * 2) = w;
      }
    }
    __syncthreads();   // S1: h_lds + x_lds(t+1) ready

    // ---- phase B: MFMA (weights stationary in registers) ----
    {
      f32x4 acc0 = {0.f, 0.f, 0.f, 0.f}, acc1 = {0.f, 0.f, 0.f, 0.f};
      const unsigned short* xl = &x_lds[t & 1][0];
      const unsigned short* hl = &h_lds[0];
      if (wv < 4) {
#pragma unroll
        for (int ks = 0; ks < 16; ks += 2) {
          bf16x8 a0 = *reinterpret_cast<const bf16x8*>(xl + c * LROW + ks * 32 + kg * 8);
          bf16x8 a1 = *reinterpret_cast<const bf16x8*>(xl + c * LROW + (ks + 1) * 32 + kg * 8);
          acc0 = __builtin_amdgcn_mfma_f32_16x16x32_bf16(a0, wfa[ks], acc0, 0, 0, 0);
          acc1 = __builtin_amdgcn_mfma_f32_16x16x32_bf16(a1, wfa[ks + 1], acc1, 0, 0, 0);
        }
#pragma unroll
        for (int ks = 0; ks < 16; ks += 2) {
          bf16x8 a0 = *reinterpret_cast<const bf16x8*>(hl + c * LROW + ks * 32 + kg * 8);
          bf16x8 a1 = *reinterpret_cast<const bf16x8*>(hl + c * LROW + (ks + 1) * 32 + kg * 8);
          acc0 = __builtin_amdgcn_mfma_f32_16x16x32_bf16(a0, wfb[ks], acc0, 0, 0, 0);
          acc1 = __builtin_amdgcn_mfma_f32_16x16x32_bf16(a1, wfb[ks + 1], acc1, 0, 0, 0);
        }
      } else if (wv < 6) {
#pragma unroll
        for (int ks = 0; ks < 16; ks += 2) {
          bf16x8 a0 = *reinterpret_cast<const bf16x8*>(xl + c * LROW + ks * 32 + kg * 8);
          bf16x8 a1 = *reinterpret_cast<const bf16x8*>(xl + c * LROW + (ks + 1) * 32 + kg * 8);
          acc0 = __builtin_amdgcn_mfma_f32_16x16x32_bf16(a0, wfa[ks], acc0, 0, 0, 0);
          acc1 = __builtin_amdgcn_mfma_f32_16x16x32_bf16(a1, wfa[ks + 1], acc1, 0, 0, 0);
        }
      } else {
#pragma unroll
        for (int ks = 0; ks < 16; ks += 2) {
          bf16x8 a0 = *reinterpret_cast<const bf16x8*>(hl + c * LROW + ks * 32 + kg * 8);
          bf16x8 a1 = *reinterpret_cast<const bf16x8*>(hl + c * LROW + (ks + 1) * 32 + kg * 8);
          acc0 = __builtin_amdgcn_mfma_f32_16x16x32_bf16(a0, wfb[ks], acc0, 0, 0, 0);
          acc1 = __builtin_amdgcn_mfma_f32_16x16x32_bf16(a1, wfb[ks + 1], acc1, 0, 0, 0);
        }
      }
      const f32x4 acc = acc0 + acc1;
      const int slot = (wv < 4) ? (wv >> 1) : ((wv < 6) ? 2 : 3);
      const int col = (wv & 1) * 16 + c;
#pragma unroll
      for (int q = 0; q < 4; ++q) s_lds[kg * 4 + q][slot][col] = acc[q];
    }
    __syncthreads();   // S2: s_lds ready

    // ---- phase C: gates (1 element per thread), outputs, tagged h broadcast ----
    {
      const float sr = s_lds[grow][0][gj] + br;
      const float sz = s_lds[grow][1][gj] + bz;
      const float si = s_lds[grow][2][gj] + bi_n;
      const float sh = s_lds[grow][3][gj] + bh_n;
      const float r = 1.f / (1.f + __expf(-sr));
      const float z = 1.f / (1.f + __expf(-sz));
      const float n = tanhf(si + r * sh);
      const float hnew = (1.f - z) * n + z * hprev;
      const bool m = (t < lenr);
      const float hk = m ? hnew : hprev;
      out[((size_t)(b0 + grow) * Tsz + t) * HD + j0 + gj] = m ? hnew : 0.f;
      hprev = hk;
      if (t == Tsz - 1) outh[(size_t)(b0 + grow) * HD + j0 + gj] = hk;
      const uint32_t ub = f2bf(hk);
      const uint32_t ot = __shfl_xor(ub, 1);
      if ((t + 1 < Tsz) && ((lane & 1) == 0)) {
        const uint32_t word = ub | (ot << 16);
        const uint64_t pkt = ((uint64_t)(uint32_t)(t + 1) << 32) | (uint64_t)word;
        __hip_atomic_store(hbx + (size_t)(t & 1) * HSLOT + (size_t)(b0 + grow) * 256 +
                               ((j0 + gj) >> 1),
                           pkt, __ATOMIC_RELAXED, __HIP_MEMORY_SCOPE_AGENT);
      }
    }
    // no end-of-step barrier: the tagged dataflow exchange self-synchronizes members;
    // S1's collectivity protects all intra-WG LDS buffer reuse across steps.
  }
}

extern "C" void kernel_launch(void* const* d_in, const int* in_sizes, int n_in,
                              void* d_out, int out_size, void* d_ws, size_t ws_size,
                              hipStream_t stream) {
  const float* x = (const float*)d_in[0];
  const float* h0 = (const float*)d_in[1];
  const float* Wih = (const float*)d_in[2];
  const float* Whh = (const float*)d_in[3];
  const float* bih = (const float*)d_in[4];
  const float* bhh = (const float*)d_in[5];
  const int* lens = (const int*)d_in[6];
  float* out = (float*)d_out;
  float* outh = out + (size_t)Bsz * Tsz * HD;

  uint64_t* hbx = (uint64_t*)d_ws;                 // [2][Bsz][HD/2] tagged bf16 pairs, 256 KB

  gru_init<<<64, 256, 0, stream>>>(h0, hbx);
  gru_persist<<<NWG, NTHR, 0, stream>>>(x, h0, Wih, Whh, bih, bhh, lens,
                                        out, outh, hbx);
}